// Round 15
// baseline (198.951 us; speedup 1.0000x reference)
//
#include <hip/hip_runtime.h>

// Cumulative product along last dim of (4096, 32768) fp32.
// ONE BLOCK (1024 thr = 16 waves) PER ROW; each wave owns a contiguous
// 2048-elem tile (8 x float4 per lane). __launch_bounds__(1024, 8) caps
// VGPR at 64 so TWO blocks co-reside per CU. In-LDS publish-and-poll
// combine (R14: 189.0us).
// vs R14: loads are PLAIN (normal L2-allocating path, like the 6.29TB/s
// copy ubench); stores stay nontemporal (isolated win, R7 vs R9).
// Single-variable test of the load hint.

#define COLS  32768
#define TPB   1024
#define NW    (TPB / 64)          // 16 waves per block
#define PERW  (COLS / NW)         // 2048 elems per wave tile
#define TCH   8                   // float4 chunks per lane
#define CHUNK 256                 // elems per chunk (64 lanes x 4)

typedef float f32x4 __attribute__((ext_vector_type(4)));

#define ONE_BITS 0x3f800000       // 1.0f bits (multiplicative identity)

template <int CTRL, int RM, int BM>
__device__ __forceinline__ float mul_dpp(float x) {
    int s = __builtin_amdgcn_update_dpp(ONE_BITS, __float_as_int(x),
                                        CTRL, RM, BM, false);
    return x * __int_as_float(s);
}

__device__ __forceinline__ float wave_scan(float t) {
    t = mul_dpp<0x111, 0xf, 0xf>(t);   // row_shr:1
    t = mul_dpp<0x112, 0xf, 0xf>(t);   // row_shr:2
    t = mul_dpp<0x114, 0xf, 0xf>(t);   // row_shr:4
    t = mul_dpp<0x118, 0xf, 0xf>(t);   // row_shr:8
    t = mul_dpp<0x142, 0xa, 0xf>(t);   // row_bcast:15 -> rows 1,3
    t = mul_dpp<0x143, 0xc, 0xf>(t);   // row_bcast:31 -> rows 2,3
    return t;
}

__device__ __forceinline__ float excl(float t) {
    return __int_as_float(__builtin_amdgcn_update_dpp(
        ONE_BITS, __float_as_int(t), 0x138, 0xf, 0xf, false));
}

__device__ __forceinline__ float read63(float t) {
    return __int_as_float(__builtin_amdgcn_readlane(__float_as_int(t), 63));
}

__global__ __launch_bounds__(TPB, 8) void cumprod_rows(
    const float* __restrict__ x, float* __restrict__ out) {

    const int lane = threadIdx.x & 63;
    const int wid  = threadIdx.x >> 6;          // 0..15

    __shared__ float wt[NW];
    if (threadIdx.x < NW) wt[threadIdx.x] = 0.0f;   // 0 == unpublished
    __syncthreads();   // cheap: before loads, all waves arrive together

    const size_t base = (size_t)blockIdx.x * COLS
                      + (size_t)wid * PERW + (size_t)lane * 4;
    const float* px = x + base;
    float*       po = out + base;

    // ---- burst-load the wave tile: 8 independent PLAIN loads ----
    f32x4 buf[TCH];
    #pragma unroll
    for (int j = 0; j < TCH; ++j)
        buf[j] = *reinterpret_cast<const f32x4*>(px + j * CHUNK);

    // ---- local scan: 4 chunk-pairs, independent DPP chains per pair ----
    float carry = 1.0f;
    #pragma unroll
    for (int pq = 0; pq < TCH / 2; ++pq) {
        f32x4 vA = buf[2 * pq], vB = buf[2 * pq + 1];
        vA[1] *= vA[0]; vB[1] *= vB[0];
        vA[2] *= vA[1]; vB[2] *= vB[1];
        vA[3] *= vA[2]; vB[3] *= vB[2];
        float tA = wave_scan(vA[3]);
        float tB = wave_scan(vB[3]);
        float exA = excl(tA), exB = excl(tB);
        float TA = read63(tA), TB = read63(tB);
        const float mA = carry * exA;
        const float cA = carry * TA;
        const float mB = cA * exB;
        carry = cA * TB;
        vA[0] *= mA; vA[1] *= mA; vA[2] *= mA; vA[3] *= mA;
        vB[0] *= mB; vB[1] *= mB; vB[2] *= mB; vB[3] *= mB;
        buf[2 * pq] = vA; buf[2 * pq + 1] = vB;
    }
    // carry == wave-tile aggregate (uniform across lanes, strictly > 0)

    // ---- publish own aggregate (release, workgroup scope) ----
    if (lane == 0)
        __hip_atomic_store(&wt[wid], carry,
                           __ATOMIC_RELEASE, __HIP_MEMORY_SCOPE_WORKGROUP);

    // ---- poll predecessors: lane l < wid polls wt[l] ----
    float v = 1.0f;
    if (lane < wid) {
        v = __hip_atomic_load(&wt[lane],
                              __ATOMIC_ACQUIRE, __HIP_MEMORY_SCOPE_WORKGROUP);
        while (v == 0.0f) {                     // lanes mask off as slots fill
            __builtin_amdgcn_s_sleep(1);
            v = __hip_atomic_load(&wt[lane],
                                  __ATOMIC_ACQUIRE, __HIP_MEMORY_SCOPE_WORKGROUP);
        }
    }
    // butterfly product over the 16-lane group (lanes >= wid contribute 1.0)
    v *= __shfl_xor(v, 1);
    v *= __shfl_xor(v, 2);
    v *= __shfl_xor(v, 4);
    v *= __shfl_xor(v, 8);
    const float p = __shfl(v, 0);               // exclusive wave prefix

    // ---- scale and burst-store; wave exits when done ----
    #pragma unroll
    for (int j = 0; j < TCH; ++j) {
        f32x4 o = buf[j];
        o[0] *= p; o[1] *= p; o[2] *= p; o[3] *= p;
        __builtin_nontemporal_store(o, reinterpret_cast<f32x4*>(po + j * CHUNK));
    }
}

extern "C" void kernel_launch(void* const* d_in, const int* in_sizes, int n_in,
                              void* d_out, int out_size, void* d_ws, size_t ws_size,
                              hipStream_t stream) {
    const float* x = (const float*)d_in[0];
    float* out = (float*)d_out;
    const int rows = out_size / COLS;           // 4096
    cumprod_rows<<<rows, TPB, 0, stream>>>(x, out);
}

// Round 16
// 188.842 us; speedup vs baseline: 1.0535x; 1.0535x over previous
//
#include <hip/hip_runtime.h>

// Cumulative product along last dim of (4096, 32768) fp32.
// ONE BLOCK (1024 thr = 16 waves) PER ROW; each wave owns a contiguous
// 2048-elem tile (8 x float4 per lane). __launch_bounds__(1024, 8) caps
// VGPR at 64 so TWO blocks co-reside per CU. In-LDS publish-and-poll
// combine. nt loads + nt stores (both isolated as wins: R15 plain-load
// 199us, R9 plain-store 228us vs this config 189us).
// BEST KNOWN CONFIG (R14: 189.0us = 5.68 TB/s = 90% of 6.29 TB/s
// read+write copy ceiling). Reverting R15's plain-load experiment.

#define COLS  32768
#define TPB   1024
#define NW    (TPB / 64)          // 16 waves per block
#define PERW  (COLS / NW)         // 2048 elems per wave tile
#define TCH   8                   // float4 chunks per lane
#define CHUNK 256                 // elems per chunk (64 lanes x 4)

typedef float f32x4 __attribute__((ext_vector_type(4)));

#define ONE_BITS 0x3f800000       // 1.0f bits (multiplicative identity)

template <int CTRL, int RM, int BM>
__device__ __forceinline__ float mul_dpp(float x) {
    int s = __builtin_amdgcn_update_dpp(ONE_BITS, __float_as_int(x),
                                        CTRL, RM, BM, false);
    return x * __int_as_float(s);
}

__device__ __forceinline__ float wave_scan(float t) {
    t = mul_dpp<0x111, 0xf, 0xf>(t);   // row_shr:1
    t = mul_dpp<0x112, 0xf, 0xf>(t);   // row_shr:2
    t = mul_dpp<0x114, 0xf, 0xf>(t);   // row_shr:4
    t = mul_dpp<0x118, 0xf, 0xf>(t);   // row_shr:8
    t = mul_dpp<0x142, 0xa, 0xf>(t);   // row_bcast:15 -> rows 1,3
    t = mul_dpp<0x143, 0xc, 0xf>(t);   // row_bcast:31 -> rows 2,3
    return t;
}

__device__ __forceinline__ float excl(float t) {
    return __int_as_float(__builtin_amdgcn_update_dpp(
        ONE_BITS, __float_as_int(t), 0x138, 0xf, 0xf, false));
}

__device__ __forceinline__ float read63(float t) {
    return __int_as_float(__builtin_amdgcn_readlane(__float_as_int(t), 63));
}

__global__ __launch_bounds__(TPB, 8) void cumprod_rows(
    const float* __restrict__ x, float* __restrict__ out) {

    const int lane = threadIdx.x & 63;
    const int wid  = threadIdx.x >> 6;          // 0..15

    __shared__ float wt[NW];
    if (threadIdx.x < NW) wt[threadIdx.x] = 0.0f;   // 0 == unpublished
    __syncthreads();   // cheap: before loads, all waves arrive together

    const size_t base = (size_t)blockIdx.x * COLS
                      + (size_t)wid * PERW + (size_t)lane * 4;
    const float* px = x + base;
    float*       po = out + base;

    // ---- burst-load the wave tile: 8 independent nt loads ----
    f32x4 buf[TCH];
    #pragma unroll
    for (int j = 0; j < TCH; ++j)
        buf[j] = __builtin_nontemporal_load(
            reinterpret_cast<const f32x4*>(px + j * CHUNK));

    // ---- local scan: 4 chunk-pairs, independent DPP chains per pair ----
    float carry = 1.0f;
    #pragma unroll
    for (int pq = 0; pq < TCH / 2; ++pq) {
        f32x4 vA = buf[2 * pq], vB = buf[2 * pq + 1];
        vA[1] *= vA[0]; vB[1] *= vB[0];
        vA[2] *= vA[1]; vB[2] *= vB[1];
        vA[3] *= vA[2]; vB[3] *= vB[2];
        float tA = wave_scan(vA[3]);
        float tB = wave_scan(vB[3]);
        float exA = excl(tA), exB = excl(tB);
        float TA = read63(tA), TB = read63(tB);
        const float mA = carry * exA;
        const float cA = carry * TA;
        const float mB = cA * exB;
        carry = cA * TB;
        vA[0] *= mA; vA[1] *= mA; vA[2] *= mA; vA[3] *= mA;
        vB[0] *= mB; vB[1] *= mB; vB[2] *= mB; vB[3] *= mB;
        buf[2 * pq] = vA; buf[2 * pq + 1] = vB;
    }
    // carry == wave-tile aggregate (uniform across lanes, strictly > 0)

    // ---- publish own aggregate (release, workgroup scope) ----
    if (lane == 0)
        __hip_atomic_store(&wt[wid], carry,
                           __ATOMIC_RELEASE, __HIP_MEMORY_SCOPE_WORKGROUP);

    // ---- poll predecessors: lane l < wid polls wt[l] ----
    float v = 1.0f;
    if (lane < wid) {
        v = __hip_atomic_load(&wt[lane],
                              __ATOMIC_ACQUIRE, __HIP_MEMORY_SCOPE_WORKGROUP);
        while (v == 0.0f) {                     // lanes mask off as slots fill
            __builtin_amdgcn_s_sleep(1);
            v = __hip_atomic_load(&wt[lane],
                                  __ATOMIC_ACQUIRE, __HIP_MEMORY_SCOPE_WORKGROUP);
        }
    }
    // butterfly product over the 16-lane group (lanes >= wid contribute 1.0)
    v *= __shfl_xor(v, 1);
    v *= __shfl_xor(v, 2);
    v *= __shfl_xor(v, 4);
    v *= __shfl_xor(v, 8);
    const float p = __shfl(v, 0);               // exclusive wave prefix

    // ---- scale and burst-store; wave exits when done ----
    #pragma unroll
    for (int j = 0; j < TCH; ++j) {
        f32x4 o = buf[j];
        o[0] *= p; o[1] *= p; o[2] *= p; o[3] *= p;
        __builtin_nontemporal_store(o, reinterpret_cast<f32x4*>(po + j * CHUNK));
    }
}

extern "C" void kernel_launch(void* const* d_in, const int* in_sizes, int n_in,
                              void* d_out, int out_size, void* d_ws, size_t ws_size,
                              hipStream_t stream) {
    const float* x = (const float*)d_in[0];
    float* out = (float*)d_out;
    const int rows = out_size / COLS;           // 4096
    cumprod_rows<<<rows, TPB, 0, stream>>>(x, out);
}